// Round 5
// baseline (248.491 us; speedup 1.0000x reference)
//
#include <hip/hip_runtime.h>
#include <hip/hip_cooperative_groups.h>

namespace cg = cooperative_groups;

#define M_ROWS  4096
#define IN_DIM  512
#define NEURONS 1024
#define OUT_DIM 512

typedef _Float16 f16;
typedef __attribute__((ext_vector_type(8))) _Float16 f16x8;
typedef __attribute__((ext_vector_type(4))) _Float16 f16x4;
typedef __attribute__((ext_vector_type(4))) float    f32x4;

// monotone float<->uint key (total order preserved on unsigned compare)
__device__ __forceinline__ unsigned fkey(float f) {
    unsigned b = __float_as_uint(f);
    return b ^ ((b & 0x80000000u) ? 0xFFFFFFFFu : 0x80000000u);
}
__device__ __forceinline__ float fdec(unsigned k) {
    unsigned b = (k & 0x80000000u) ? (k ^ 0x80000000u) : ~k;
    return __uint_as_float(b);
}

// ---------------------------------------------------------------------------
// Generic fp16 MFMA GEMM body, BK=64, global_load_lds(16B), linear LDS
// [row][64], double-buffered, one barrier per K-step. 4 waves in 2x2.
// OUTMODE 0: f16 C + fused per-row min/max atomics. OUTMODE 1: f32 bias+ReLU.
// ---------------------------------------------------------------------------
template<int BM, int BN, int MI, int NJ, int OUTMODE>
__device__ __forceinline__ void gemm_body(
    f16* sm, const f16* __restrict__ A, const f16* __restrict__ Bt,
    const float* __restrict__ bias, void* __restrict__ Cout,
    unsigned* __restrict__ minkey, unsigned* __restrict__ maxkey,
    int N, int K, int m0, int n0)
{
    constexpr int CA = BM / 32;          // A 1KB chunks per wave per K-step
    constexpr int CB = BN / 32;
    constexpr int TILE = (BM + BN) * 64; // f16 elements per buffer

    const int t    = threadIdx.x;
    const int lane = t & 63;
    const int l15  = lane & 15;
    const int lhi  = lane >> 4;
    const int wid  = t >> 6;
    const int wm   = wid >> 1, wn = wid & 1;

    auto stage = [&](int buf, int kt) {
        f16* base = sm + buf * TILE;
#pragma unroll
        for (int j = 0; j < CA; ++j) {
            int c = wid * CA + j;        // chunk = 8 rows x 64 k
            const f16* g = A + (size_t)(m0 + c * 8 + (lane >> 3)) * K + kt + (lane & 7) * 8;
            __builtin_amdgcn_global_load_lds(
                (const __attribute__((address_space(1))) void*)g,
                (__attribute__((address_space(3))) void*)(base + c * 512),
                16, 0, 0);
        }
#pragma unroll
        for (int j = 0; j < CB; ++j) {
            int c = wid * CB + j;
            const f16* g = Bt + (size_t)(n0 + c * 8 + (lane >> 3)) * K + kt + (lane & 7) * 8;
            __builtin_amdgcn_global_load_lds(
                (const __attribute__((address_space(1))) void*)g,
                (__attribute__((address_space(3))) void*)(base + BM * 64 + c * 512),
                16, 0, 0);
        }
    };

    f32x4 acc[MI][NJ];
#pragma unroll
    for (int i = 0; i < MI; ++i)
#pragma unroll
        for (int j = 0; j < NJ; ++j) acc[i][j] = (f32x4)0.f;

    const int T = K / 64;
    stage(0, 0);
    __syncthreads();

    int cur = 0;
    for (int tt = 0; tt < T; ++tt) {
        if (tt + 1 < T) stage(cur ^ 1, (tt + 1) * 64);
        const f16* L = sm + cur * TILE;
#pragma unroll
        for (int ks = 0; ks < 2; ++ks) {
            f16x8 bfr[NJ];
#pragma unroll
            for (int nj = 0; nj < NJ; ++nj)
                bfr[nj] = *(const f16x8*)
                    &L[BM * 64 + (wn * NJ * 16 + nj * 16 + l15) * 64 + ks * 32 + lhi * 8];
#pragma unroll
            for (int mi = 0; mi < MI; ++mi) {
                f16x8 afr = *(const f16x8*)
                    &L[(wm * MI * 16 + mi * 16 + l15) * 64 + ks * 32 + lhi * 8];
#pragma unroll
                for (int nj = 0; nj < NJ; ++nj)
                    acc[mi][nj] = __builtin_amdgcn_mfma_f32_16x16x32_f16(
                        afr, bfr[nj], acc[mi][nj], 0, 0, 0);
            }
        }
        __syncthreads();
        cur ^= 1;
    }

    // epilogue: C/D map col = l15, row = lhi*4 + j
#pragma unroll
    for (int mi = 0; mi < MI; ++mi) {
        const int row0 = m0 + wm * MI * 16 + mi * 16 + lhi * 4;
        if (OUTMODE == 0) {
            f16* H = (f16*)Cout;
            float vmn[4], vmx[4];
#pragma unroll
            for (int nj = 0; nj < NJ; ++nj) {
                int col = n0 + wn * NJ * 16 + nj * 16 + l15;
                float bv = bias[col];
#pragma unroll
                for (int j = 0; j < 4; ++j) {
                    f16 hv = (f16)(acc[mi][nj][j] + bv);
                    H[(size_t)(row0 + j) * N + col] = hv;
                    float vr = (float)hv;     // min/max of the ROUNDED value
                    if (nj == 0) { vmn[j] = vr; vmx[j] = vr; }
                    else { vmn[j] = fminf(vmn[j], vr); vmx[j] = fmaxf(vmx[j], vr); }
                }
            }
#pragma unroll
            for (int j = 0; j < 4; ++j) {
#pragma unroll
                for (int d = 1; d < 16; d <<= 1) {
                    vmn[j] = fminf(vmn[j], __shfl_xor(vmn[j], d));
                    vmx[j] = fmaxf(vmx[j], __shfl_xor(vmx[j], d));
                }
            }
            if (l15 == 0) {
#pragma unroll
                for (int j = 0; j < 4; ++j) {
                    atomicMin(&minkey[row0 + j], fkey(vmn[j]));
                    atomicMax(&maxkey[row0 + j], fkey(vmx[j]));
                }
            }
        } else {
            float* O = (float*)Cout;
#pragma unroll
            for (int nj = 0; nj < NJ; ++nj) {
                int col = n0 + wn * NJ * 16 + nj * 16 + l15;
                float bv = bias[col];
#pragma unroll
                for (int j = 0; j < 4; ++j) {
                    float v = fmaxf(acc[mi][nj][j] + bv, 0.f);
                    O[(size_t)(row0 + j) * N + col] = v;
                }
            }
        }
    }
}

// ---------------------------------------------------------------------------
// Single cooperative kernel: P0 prep -> P1 GEMM1+minmax -> P2 spline -> P3 GEMM2
// 512 blocks x 256 threads, grid.sync() between phases.
// ---------------------------------------------------------------------------
__global__ __launch_bounds__(256, 2) void fused_all(
    const float* __restrict__ x,  const float* __restrict__ W1,
    const float* __restrict__ b1, const float* __restrict__ coeff,
    const float* __restrict__ spb, const float* __restrict__ W2,
    const float* __restrict__ b2, float* __restrict__ out,
    f16* __restrict__ h, f16* __restrict__ sph, f16* __restrict__ xh,
    f16* __restrict__ W1t, f16* __restrict__ W2t,
    unsigned* __restrict__ minkey, unsigned* __restrict__ maxkey)
{
    __shared__ __align__(16) char smem[49152];
    cg::grid_group grid = cg::this_grid();
    const int b = blockIdx.x, t = threadIdx.x;

    // ---------------- P0: prep (2080 work units over 512 blocks) ------------
    for (int u = b; u < 2080; u += 512) {
        if (u < 1024) {                       // x f32 -> f16, 8 elems/thread
            int i = u * 256 + t;
            const float4* p = (const float4*)x;
            float4 a = p[i * 2], c = p[i * 2 + 1];
            f16x8 o = { (f16)a.x, (f16)a.y, (f16)a.z, (f16)a.w,
                        (f16)c.x, (f16)c.y, (f16)c.z, (f16)c.w };
            *(f16x8*)(xh + (size_t)i * 8) = o;
        } else if (u < 2048) {                // W transposes via LDS 32x32
            float (*S)[33] = (float(*)[33])smem;
            const float* src; f16* dst; int R, C, tile;
            if (u < 1536) { src = W1; dst = W1t; R = IN_DIM;  C = NEURONS; tile = u - 1024; }
            else          { src = W2; dst = W2t; R = NEURONS; C = OUT_DIM; tile = u - 1536; }
            const int ntx = C / 32;
            const int tx = tile % ntx, ty = tile / ntx;
            const int tr = t >> 3, tc = (t & 7) * 4;
            float4 v = *(const float4*)&src[(size_t)(ty * 32 + tr) * C + tx * 32 + tc];
            __syncthreads();                  // protect S from prior unit's readers
            S[tr][tc + 0] = v.x; S[tr][tc + 1] = v.y;
            S[tr][tc + 2] = v.z; S[tr][tc + 3] = v.w;
            __syncthreads();
            f16x4 o = { (f16)S[tc + 0][tr], (f16)S[tc + 1][tr],
                        (f16)S[tc + 2][tr], (f16)S[tc + 3][tr] };
            *(f16x4*)&dst[(size_t)(tx * 32 + tr) * R + ty * 32 + tc] = o;
        } else {                              // init min/max keys
            int i = (u - 2048) * 256 + t;     // 0..8191
            ((unsigned*)minkey)[i] = (i < 4096) ? 0xFFFFFFFFu : 0u;  // [min|max]
        }
    }
    grid.sync();

    // ---------------- P1: GEMM1  h = x @ W1 + b1 (f16 out, minmax) ---------
    {
        const int swz = (b & 7) * 64 + (b >> 3);        // 512 tiles, 8 XCDs
        const int m0 = (swz / 16) * 128;                // gx = 1024/64 = 16
        const int n0 = (swz % 16) * 64;
        gemm_body<128, 64, 4, 2, 0>((f16*)smem, xh, W1t, b1, h,
                                    minkey, maxkey, NEURONS, IN_DIM, m0, n0);
    }
    grid.sync();

    // ---------------- P2: norm + spline -> sph (f16) ------------------------
    {
        const float hk = 1.0f / 15.0f;
#pragma unroll
        for (int it = 0; it < 4; ++it) {
            const int row = b * 8 + it * 2 + (t >> 7);
            const int tt  = t & 127;
            const float mn = fdec(minkey[row]);
            const float mx = fdec(maxkey[row]);
            const float inv = 1.0f / (mx - mn + 1e-8f);
            f16x8 hv = *(const f16x8*)&h[(size_t)row * NEURONS + tt * 8];
            f16x8 o;
#pragma unroll
            for (int e = 0; e < 8; ++e) {
                const int n = tt * 8 + e;
                const float u = ((float)hv[e] - mn) * inv;
                int ii = (int)floorf(u * 15.0f);
                ii = ii < 0 ? 0 : (ii > 14 ? 14 : ii);
                const int i = ii + 3;
                float Bv[4] = {1.f, 0.f, 0.f, 0.f};
#pragma unroll
                for (int p = 1; p <= 3; ++p) {
                    const float dinv = 1.0f / ((float)p * hk);
                    float nb[4];
#pragma unroll
                    for (int j = 3; j >= 0; --j) {
                        if (j > p) { nb[j] = 0.f; continue; }
                        const int m = i - p + j;
                        const float tm   = (float)(m - 3) * hk;
                        const float tmp1 = (float)(m + p + 1 - 3) * hk;
                        const float left  = (j > 0) ? (u - tm)   * Bv[j - 1] : 0.f;
                        const float right = (j < p) ? (tmp1 - u) * Bv[j]     : 0.f;
                        nb[j] = (left + right) * dinv;
                    }
#pragma unroll
                    for (int j = 0; j < 4; ++j) Bv[j] = nb[j];
                }
                const float* c = coeff + (size_t)n * 18 + ii;
                float sp = fmaf(Bv[0], c[0],
                           fmaf(Bv[1], c[1],
                           fmaf(Bv[2], c[2], Bv[3] * c[3]))) + spb[n];
                o[e] = (f16)sp;
            }
            *(f16x8*)&sph[(size_t)row * NEURONS + tt * 8] = o;
        }
    }
    grid.sync();

    // ---------------- P3: GEMM2  out = relu(sp @ W2 + b2) -------------------
    {
        const int swz = (b & 7) * 64 + (b >> 3);        // 512 tiles of 64x64
        const int m0 = (swz / 8) * 64;                  // gx = 512/64 = 8
        const int n0 = (swz % 8) * 64;
        gemm_body<64, 64, 2, 2, 1>((f16*)smem, sph, W2t, b2, out,
                                   nullptr, nullptr, OUT_DIM, NEURONS, m0, n0);
    }
}

// ---------------------------------------------------------------------------
extern "C" void kernel_launch(void* const* d_in, const int* in_sizes, int n_in,
                              void* d_out, int out_size, void* d_ws, size_t ws_size,
                              hipStream_t stream)
{
    const float* x     = (const float*)d_in[0];
    const float* W1    = (const float*)d_in[1];
    const float* b1    = (const float*)d_in[2];
    const float* coeff = (const float*)d_in[3];
    const float* spb   = (const float*)d_in[4];
    const float* W2    = (const float*)d_in[5];
    const float* b2    = (const float*)d_in[6];
    float* out = (float*)d_out;

    char* ws = (char*)d_ws;
    f16*      h      = (f16*)ws;                       //  8 MB [4096][1024]
    f16*      sph    = (f16*)(ws + (8u  << 20));       //  8 MB [4096][1024]
    f16*      xh     = (f16*)(ws + (16u << 20));       //  4 MB [4096][512]
    f16*      W1t    = (f16*)(ws + (20u << 20));       //  1 MB [1024][512]
    f16*      W2t    = (f16*)(ws + (21u << 20));       //  1 MB [512][1024]
    unsigned* minkey = (unsigned*)(ws + (22u << 20));  // 16 KB
    unsigned* maxkey = minkey + 4096;                  // 16 KB

    void* args[] = { (void*)&x, (void*)&W1, (void*)&b1, (void*)&coeff,
                     (void*)&spb, (void*)&W2, (void*)&b2, (void*)&out,
                     (void*)&h, (void*)&sph, (void*)&xh, (void*)&W1t,
                     (void*)&W2t, (void*)&minkey, (void*)&maxkey };
    hipLaunchCooperativeKernel((const void*)fused_all, dim3(512), dim3(256),
                               args, 0, stream);
}

// Round 6
// 217.175 us; speedup vs baseline: 1.1442x; 1.1442x over previous
//
#include <hip/hip_runtime.h>

#define M_ROWS  4096
#define IN_DIM  512
#define NEURONS 1024
#define OUT_DIM 512

typedef _Float16 f16;
typedef __attribute__((ext_vector_type(8))) _Float16 f16x8;
typedef __attribute__((ext_vector_type(4))) _Float16 f16x4;
typedef __attribute__((ext_vector_type(4))) float    f32x4;

// ===========================================================================
// K_a: self-contained GEMM1  h = f16(x @ W1 + b1)
//   - A: reg-stage x f32 -> f16 into padded LDS [128][72]
//   - B: reg-stage W1 transpose f32 -> f16 into padded LDS [64][72]
//   - epilogue: h f16 + per-(row, n-block) min/max partials (direct stores)
//   - tail: W2 -> W2t f16 (pre-XOR-swizzled k-chunks), cp coeff-window table
// ===========================================================================
__global__ __launch_bounds__(256) void k_gemm1(
    const float* __restrict__ x,  const float* __restrict__ W1,
    const float* __restrict__ b1, const float* __restrict__ coeff,
    const float* __restrict__ spb, const float* __restrict__ W2,
    f16* __restrict__ h, float* __restrict__ pmin, float* __restrict__ pmax,
    f16* __restrict__ W2t, float* __restrict__ cp)
{
    __shared__ __align__(16) char smem[55296];
    f16* Ab = (f16*)smem;                 // [2][128*72]
    f16* Bb = (f16*)(smem + 36864);       // [2][64*72]

    const int t    = threadIdx.x;
    const int lane = t & 63, l15 = lane & 15, lhi = lane >> 4;
    const int wid  = t >> 6;

    // 512 blocks = 32 m-tiles x 16 n-tiles; chunked XCD swizzle, n-major
    const int flat = blockIdx.x;
    const int swz  = (flat & 7) * 64 + (flat >> 3);
    const int m0   = (swz >> 4) * 128;
    const int n0   = (swz & 15) * 64;

    // A staging: thread -> row sm_, k-half skh (32 k each)
    const int sm_ = t >> 1, skh = (t & 1) * 32;
    const float* xp = x + (size_t)(m0 + sm_) * IN_DIM + skh;
    // B staging: thread -> k-row bk, n-chunk bc (16 cols)
    const int bk = t & 63, bc = t >> 6;
    const float* wp = W1 + (size_t)bk * NEURONS + n0 + bc * 16;

    float4 ar[8], br[4];
    auto gload = [&](int kt) {
#pragma unroll
        for (int c = 0; c < 8; ++c)
            ar[c] = *(const float4*)(xp + kt + c * 4);
#pragma unroll
        for (int q = 0; q < 4; ++q)
            br[q] = *(const float4*)(wp + (size_t)kt * NEURONS + q * 4);
    };
    auto swrite = [&](int buf) {
        f16* A_ = Ab + buf * (128 * 72);
#pragma unroll
        for (int c = 0; c < 8; ++c) {
            f16x4 o = {(f16)ar[c].x, (f16)ar[c].y, (f16)ar[c].z, (f16)ar[c].w};
            *(f16x4*)&A_[sm_ * 72 + skh + c * 4] = o;
        }
        f16* B_ = Bb + buf * (64 * 72);
#pragma unroll
        for (int q = 0; q < 4; ++q) {
            B_[(bc * 16 + q * 4 + 0) * 72 + bk] = (f16)br[q].x;
            B_[(bc * 16 + q * 4 + 1) * 72 + bk] = (f16)br[q].y;
            B_[(bc * 16 + q * 4 + 2) * 72 + bk] = (f16)br[q].z;
            B_[(bc * 16 + q * 4 + 3) * 72 + bk] = (f16)br[q].w;
        }
    };

    f32x4 acc[2][4];
#pragma unroll
    for (int i = 0; i < 2; ++i)
#pragma unroll
        for (int j = 0; j < 4; ++j) acc[i][j] = (f32x4)0.f;

    gload(0);
    swrite(0);
    __syncthreads();

    int cur = 0;
    for (int tt = 0; tt < 8; ++tt) {          // K = 512, BK = 64
        if (tt < 7) gload((tt + 1) * 64);
        const f16* A_ = Ab + cur * (128 * 72);
        const f16* B_ = Bb + cur * (64 * 72);
#pragma unroll
        for (int ks = 0; ks < 2; ++ks) {
            f16x8 bfr[4];
#pragma unroll
            for (int nj = 0; nj < 4; ++nj)
                bfr[nj] = *(const f16x8*)&B_[(nj * 16 + l15) * 72 + ks * 32 + lhi * 8];
#pragma unroll
            for (int mi = 0; mi < 2; ++mi) {
                f16x8 afr = *(const f16x8*)
                    &A_[(wid * 32 + mi * 16 + l15) * 72 + ks * 32 + lhi * 8];
#pragma unroll
                for (int nj = 0; nj < 4; ++nj)
                    acc[mi][nj] = __builtin_amdgcn_mfma_f32_16x16x32_f16(
                        afr, bfr[nj], acc[mi][nj], 0, 0, 0);
            }
        }
        if (tt < 7) swrite(cur ^ 1);
        __syncthreads();
        cur ^= 1;
    }

    // epilogue: C/D map col=l15, row=lhi*4+j; h f16 + minmax partials
    const int nb = n0 >> 6;
#pragma unroll
    for (int mi = 0; mi < 2; ++mi) {
        const int row0 = m0 + wid * 32 + mi * 16 + lhi * 4;
        float vmn[4], vmx[4];
#pragma unroll
        for (int nj = 0; nj < 4; ++nj) {
            const int col = n0 + nj * 16 + l15;
            const float bv = b1[col];
#pragma unroll
            for (int j = 0; j < 4; ++j) {
                f16 hv = (f16)(acc[mi][nj][j] + bv);
                h[(size_t)(row0 + j) * NEURONS + col] = hv;
                float vr = (float)hv;               // min/max of ROUNDED value
                if (nj == 0) { vmn[j] = vr; vmx[j] = vr; }
                else { vmn[j] = fminf(vmn[j], vr); vmx[j] = fmaxf(vmx[j], vr); }
            }
        }
#pragma unroll
        for (int j = 0; j < 4; ++j) {
#pragma unroll
            for (int d = 1; d < 16; d <<= 1) {
                vmn[j] = fminf(vmn[j], __shfl_xor(vmn[j], d));
                vmx[j] = fmaxf(vmx[j], __shfl_xor(vmx[j], d));
            }
        }
        if (l15 == 0) {
#pragma unroll
            for (int j = 0; j < 4; ++j) {
                pmin[(size_t)nb * M_ROWS + row0 + j] = vmn[j];
                pmax[(size_t)nb * M_ROWS + row0 + j] = vmx[j];
            }
        }
    }

    // ---- tail 1: W2 -> W2t f16, pre-swizzled: byte ^= ((n&7)<<4) in k ------
    __syncthreads();
    {
        float (*S)[33] = (float(*)[33])smem;
        const int nt = flat & 15, kt2 = flat >> 4;     // 16 n-tiles x 32 k-tiles
        const int tr = t >> 3, tc4 = (t & 7) * 4;
        float4 v = *(const float4*)&W2[(size_t)(kt2 * 32 + tr) * OUT_DIM + nt * 32 + tc4];
        S[tr][tc4 + 0] = v.x; S[tr][tc4 + 1] = v.y;
        S[tr][tc4 + 2] = v.z; S[tr][tc4 + 3] = v.w;
        __syncthreads();
        const int n = nt * 32 + tr;
        f16x4 o = {(f16)S[tc4 + 0][tr], (f16)S[tc4 + 1][tr],
                   (f16)S[tc4 + 2][tr], (f16)S[tc4 + 3][tr]};
        const int kbyte = ((kt2 * 32 + tc4) * 2) ^ ((n & 7) << 4);
        *(f16x4*)((char*)W2t + (size_t)n * 2048 + kbyte) = o;
    }

    // ---- tail 2: cp[n][ii] = coeff window + spb (partition of unity) -------
    {
        const int tid = flat * 256 + t;
        if (tid < NEURONS * 15) {
            const int n = tid / 15, ii = tid % 15;
            const float s = spb[n];
            float4 c;
            c.x = coeff[n * 18 + ii]     + s;
            c.y = coeff[n * 18 + ii + 1] + s;
            c.z = coeff[n * 18 + ii + 2] + s;
            c.w = coeff[n * 18 + ii + 3] + s;
            *(float4*)&cp[(size_t)tid * 4] = c;
        }
    }
}

// ===========================================================================
// K_b: fused spline + GEMM2   out = relu(spline(norm(h)) @ W2 + b2)
//   A-fragments produced in REGISTERS by per-lane spline (2 phases x 8 steps)
//   B staged via linear global_load_lds from pre-swizzled W2t, XOR on ds_read
// ===========================================================================
__global__ __launch_bounds__(256) void k_spline_gemm2(
    const f16* __restrict__ h, const float* __restrict__ pmin,
    const float* __restrict__ pmax, const float* __restrict__ cp,
    const f16* __restrict__ W2t, const float* __restrict__ b2,
    float* __restrict__ out)
{
    __shared__ __align__(16) f16 Bb[2][128 * 64];

    const int t    = threadIdx.x;
    const int lane = t & 63, l15 = lane & 15, lhi = lane >> 4;
    const int wid  = t >> 6;

    // 512 blocks = 128 m-tiles x 4 n-tiles; chunked XCD swizzle, n-major
    const int flat = blockIdx.x;
    const int swz  = (flat & 7) * 64 + (flat >> 3);
    const int m0   = (swz >> 2) * 32;
    const int n0   = (swz & 3) * 128;

    auto stage = [&](int buf, int kt) {
        char* base = (char*)&Bb[buf][0] + wid * 4096;
#pragma unroll
        for (int j = 0; j < 4; ++j) {
            const int r  = wid * 32 + j * 8 + (lane >> 3);
            const int kc = lane & 7;
            const char* src = (const char*)W2t + (size_t)(n0 + r) * 2048 + kt * 2 + kc * 16;
            __builtin_amdgcn_global_load_lds(
                (const __attribute__((address_space(1))) void*)src,
                (__attribute__((address_space(3))) void*)(base + j * 1024),
                16, 0, 0);
        }
    };

    // reduce the 16 min/max partials for this block's 32 rows
    float mn[2], mx[2], inv[2];
#pragma unroll
    for (int mi = 0; mi < 2; ++mi) {
        const int row = m0 + mi * 16 + l15;
        float a = pmin[row], b = pmax[row];
#pragma unroll
        for (int p = 1; p < 16; ++p) {
            a = fminf(a, pmin[(size_t)p * M_ROWS + row]);
            b = fmaxf(b, pmax[(size_t)p * M_ROWS + row]);
        }
        mn[mi] = a; mx[mi] = b;
        inv[mi] = 1.0f / (b - a + 1e-8f);
    }

    f32x4 acc[2][2];
#pragma unroll
    for (int i = 0; i < 2; ++i)
#pragma unroll
        for (int j = 0; j < 2; ++j) acc[i][j] = (f32x4)0.f;

    stage(0, 0);

    int cur = 0;
#pragma unroll
    for (int p = 0; p < 2; ++p) {
        // ---- spline phase: fill A-fragments for 8 K-steps into registers ---
        f16x8 a_[8][2][2];
#pragma unroll
        for (int tq = 0; tq < 8; ++tq) {
            const int tt = p * 8 + tq;
#pragma unroll
            for (int ks = 0; ks < 2; ++ks) {
#pragma unroll
                for (int mi = 0; mi < 2; ++mi) {
                    const int row = m0 + mi * 16 + l15;
                    const int kg  = tt * 64 + ks * 32 + lhi * 8;
                    f16x8 hv = *(const f16x8*)&h[(size_t)row * NEURONS + kg];
                    f16x8 o;
#pragma unroll
                    for (int e = 0; e < 8; ++e) {
                        const float u   = ((float)hv[e] - mn[mi]) * inv[mi];
                        const float t15 = u * 15.0f;
                        int ii = (int)t15;
                        ii = ii < 0 ? 0 : (ii > 14 ? 14 : ii);
                        const float tl  = t15 - (float)ii;
                        const float t2  = tl * tl, t3 = t2 * tl;
                        const float omt = 1.0f - tl;
                        const float b0  = omt * omt * omt * (1.0f / 6.0f);
                        const float b3v = t3 * (1.0f / 6.0f);
                        const float b1v = (4.0f / 6.0f) - t2 + 0.5f * t3;
                        const float b2v = (1.0f / 6.0f) + 0.5f * (tl + t2 - t3);
                        const float4 c = *(const float4*)
                            &cp[((size_t)(kg + e) * 15 + ii) * 4];
                        o[e] = (f16)(c.x * b0 + c.y * b1v + c.z * b2v + c.w * b3v);
                    }
                    a_[tq][ks][mi] = o;
                }
            }
        }
        __syncthreads();   // p==0: stage(0) visible; p==1: harmless re-sync

        // ---- 8 GEMM steps ---------------------------------------------------
#pragma unroll
        for (int tq = 0; tq < 8; ++tq) {
            const int tt = p * 8 + tq;
            if (tt < 15) stage(cur ^ 1, (tt + 1) * 64);
            const char* B_ = (const char*)&Bb[cur][0];
#pragma unroll
            for (int ks = 0; ks < 2; ++ks) {
#pragma unroll
                for (int nj = 0; nj < 2; ++nj) {
                    const int col = wid * 32 + nj * 16 + l15;
                    const int kb  = (ks * 64 + lhi * 16) ^ ((col & 7) << 4);
                    f16x8 bfr = *(const f16x8*)(B_ + col * 128 + kb);
#pragma unroll
                    for (int mi = 0; mi < 2; ++mi)
                        acc[mi][nj] = __builtin_amdgcn_mfma_f32_16x16x32_f16(
                            a_[tq][ks][mi], bfr, acc[mi][nj], 0, 0, 0);
                }
            }
            __syncthreads();
            cur ^= 1;
        }
    }

    // epilogue: bias + relu, f32
#pragma unroll
    for (int mi = 0; mi < 2; ++mi) {
        const int row0 = m0 + mi * 16 + lhi * 4;
#pragma unroll
        for (int nj = 0; nj < 2; ++nj) {
            const int col = n0 + wid * 32 + nj * 16 + l15;
            const float bv = b2[col];
#pragma unroll
            for (int j = 0; j < 4; ++j)
                out[(size_t)(row0 + j) * OUT_DIM + col] =
                    fmaxf(acc[mi][nj][j] + bv, 0.0f);
        }
    }
}

// ===========================================================================
extern "C" void kernel_launch(void* const* d_in, const int* in_sizes, int n_in,
                              void* d_out, int out_size, void* d_ws, size_t ws_size,
                              hipStream_t stream)
{
    const float* x     = (const float*)d_in[0];
    const float* W1    = (const float*)d_in[1];
    const float* b1    = (const float*)d_in[2];
    const float* coeff = (const float*)d_in[3];
    const float* spb   = (const float*)d_in[4];
    const float* W2    = (const float*)d_in[5];
    const float* b2    = (const float*)d_in[6];
    float* out = (float*)d_out;

    char* ws = (char*)d_ws;
    f16*   h    = (f16*)ws;                                   // 8 MB [4096][1024]
    f16*   W2t  = (f16*)(ws + (8u << 20));                    // 1 MB [512][1024] (pre-swizzled)
    float* pmin = (float*)(ws + (9u << 20));                  // 256 KB [16][4096]
    float* pmax = (float*)(ws + (9u << 20) + (256u << 10));   // 256 KB
    float* cp   = (float*)(ws + (10u << 20));                 // 960 KB [1024][15][4]

    k_gemm1<<<512, 256, 0, stream>>>(x, W1, b1, coeff, spb, W2,
                                     h, pmin, pmax, W2t, cp);
    k_spline_gemm2<<<512, 256, 0, stream>>>(h, pmin, pmax, cp, W2t, b2, out);
}

// Round 7
// 50.043 us; speedup vs baseline: 4.9656x; 4.3398x over previous
//
#include <hip/hip_runtime.h>

#define M_ROWS  4096
#define IN_DIM  512
#define NEURONS 1024
#define OUT_DIM 512

typedef _Float16 f16;
typedef __attribute__((ext_vector_type(8))) _Float16 f16x8;
typedef __attribute__((ext_vector_type(4))) _Float16 f16x4;
typedef __attribute__((ext_vector_type(4))) float    f32x4;

// ===========================================================================
// prep:
//  [0,1024)    x f32 -> xh f16
//  [1024,1536) W1 [512][1024] -> W1t [1024][512] f16
//  [1536,2048) W2 [1024][512] -> W2t [512][1024] f16, pre-XOR-swizzled k-chunks
//  [2048,2108) cp[n][ii][4] = coeff window + spb (partition of unity)
// ===========================================================================
__global__ __launch_bounds__(256) void prep(
    const float* __restrict__ x,  f16* __restrict__ xh,
    const float* __restrict__ W1, f16* __restrict__ W1t,
    const float* __restrict__ W2, f16* __restrict__ W2t,
    const float* __restrict__ coeff, const float* __restrict__ spb,
    float* __restrict__ cp)
{
    __shared__ float S[32][33];
    const int b = blockIdx.x, t = threadIdx.x;
    if (b < 1024) {
        int i = b * 256 + t;
        const float4* p = (const float4*)x;
        float4 a = p[i * 2], c = p[i * 2 + 1];
        f16x8 o = { (f16)a.x, (f16)a.y, (f16)a.z, (f16)a.w,
                    (f16)c.x, (f16)c.y, (f16)c.z, (f16)c.w };
        *(f16x8*)(xh + (size_t)i * 8) = o;
        return;
    }
    if (b < 1536) {                       // W1 transpose -> f16
        const int tile = b - 1024;
        const int tx = tile & 31, ty = tile >> 5;     // 32 x-tiles, 16 y-tiles
        const int tr = t >> 3, tc = (t & 7) * 4;
        float4 v = *(const float4*)&W1[(size_t)(ty * 32 + tr) * NEURONS + tx * 32 + tc];
        S[tr][tc + 0] = v.x; S[tr][tc + 1] = v.y;
        S[tr][tc + 2] = v.z; S[tr][tc + 3] = v.w;
        __syncthreads();
        f16x4 o = {(f16)S[tc + 0][tr], (f16)S[tc + 1][tr],
                   (f16)S[tc + 2][tr], (f16)S[tc + 3][tr]};
        *(f16x4*)&W1t[(size_t)(tx * 32 + tr) * IN_DIM + ty * 32 + tc] = o;
        return;
    }
    if (b < 2048) {                       // W2 transpose -> f16, swizzled
        const int tile = b - 1536;
        const int nt = tile & 15, kt2 = tile >> 4;    // 16 n-tiles, 32 k-tiles
        const int tr = t >> 3, tc4 = (t & 7) * 4;
        float4 v = *(const float4*)&W2[(size_t)(kt2 * 32 + tr) * OUT_DIM + nt * 32 + tc4];
        S[tr][tc4 + 0] = v.x; S[tr][tc4 + 1] = v.y;
        S[tr][tc4 + 2] = v.z; S[tr][tc4 + 3] = v.w;
        __syncthreads();
        const int n = nt * 32 + tr;
        f16x4 o = {(f16)S[tc4 + 0][tr], (f16)S[tc4 + 1][tr],
                   (f16)S[tc4 + 2][tr], (f16)S[tc4 + 3][tr]};
        const int kbyte = ((kt2 * 32 + tc4) * 2) ^ ((n & 7) << 4);
        *(f16x4*)((char*)W2t + (size_t)n * 2048 + kbyte) = o;
        return;
    }
    {                                     // cp table
        const int tid = (b - 2048) * 256 + t;
        if (tid < NEURONS * 15) {
            const int n = tid / 15, ii = tid % 15;
            const float s = spb[n];
            float4 c;
            c.x = coeff[n * 18 + ii]     + s;
            c.y = coeff[n * 18 + ii + 1] + s;
            c.z = coeff[n * 18 + ii + 2] + s;
            c.w = coeff[n * 18 + ii + 3] + s;
            *(float4*)&cp[(size_t)tid * 4] = c;
        }
    }
}

// ===========================================================================
// gemm1: h(f16) = x @ W1 + b1, BM=128 BN=64 BK=64, global_load_lds(16B),
// linear LDS [row][64], dbuf, 1 barrier/step. Partial min/max stores:
// pmin/pmax[(n0/64)*2 + wn][row]  (32 partials per row, no atomics/init).
// ===========================================================================
__global__ __launch_bounds__(256) void k_gemm1(
    const f16* __restrict__ A, const f16* __restrict__ Bt,
    const float* __restrict__ b1, f16* __restrict__ h,
    float* __restrict__ pmin, float* __restrict__ pmax)
{
    __shared__ f16 lds[2][(128 + 64) * 64];   // 48 KB

    const int t    = threadIdx.x;
    const int lane = t & 63, l15 = lane & 15, lhi = lane >> 4;
    const int wid  = t >> 6;
    const int wm   = wid >> 1, wn = wid & 1;

    const int flat = blockIdx.y * gridDim.x + blockIdx.x;   // 512 blocks
    const int swz  = (flat & 7) * 64 + (flat >> 3);
    const int m0   = (swz >> 4) * 128;
    const int n0   = (swz & 15) * 64;

    auto stage = [&](int buf, int kt) {
        f16* base = &lds[buf][0];
#pragma unroll
        for (int j = 0; j < 4; ++j) {                    // A: 16 chunks of 8 rows
            int c = wid * 4 + j;
            const f16* g = A + (size_t)(m0 + c * 8 + (lane >> 3)) * IN_DIM + kt + (lane & 7) * 8;
            __builtin_amdgcn_global_load_lds(
                (const __attribute__((address_space(1))) void*)g,
                (__attribute__((address_space(3))) void*)(base + c * 512), 16, 0, 0);
        }
#pragma unroll
        for (int j = 0; j < 2; ++j) {                    // B: 8 chunks
            int c = wid * 2 + j;
            const f16* g = Bt + (size_t)(n0 + c * 8 + (lane >> 3)) * IN_DIM + kt + (lane & 7) * 8;
            __builtin_amdgcn_global_load_lds(
                (const __attribute__((address_space(1))) void*)g,
                (__attribute__((address_space(3))) void*)(base + 8192 + c * 512), 16, 0, 0);
        }
    };

    f32x4 acc[4][2];
#pragma unroll
    for (int i = 0; i < 4; ++i)
#pragma unroll
        for (int j = 0; j < 2; ++j) acc[i][j] = (f32x4)0.f;

    stage(0, 0);
    __syncthreads();

    int cur = 0;
    for (int tt = 0; tt < 8; ++tt) {                     // K = 512
        if (tt < 7) stage(cur ^ 1, (tt + 1) * 64);
        const f16* L = &lds[cur][0];
#pragma unroll
        for (int ks = 0; ks < 2; ++ks) {
            f16x8 bfr[2];
#pragma unroll
            for (int nj = 0; nj < 2; ++nj)
                bfr[nj] = *(const f16x8*)
                    &L[8192 + (wn * 32 + nj * 16 + l15) * 64 + ks * 32 + lhi * 8];
#pragma unroll
            for (int mi = 0; mi < 4; ++mi) {
                f16x8 afr = *(const f16x8*)
                    &L[(wm * 64 + mi * 16 + l15) * 64 + ks * 32 + lhi * 8];
#pragma unroll
                for (int nj = 0; nj < 2; ++nj)
                    acc[mi][nj] = __builtin_amdgcn_mfma_f32_16x16x32_f16(
                        afr, bfr[nj], acc[mi][nj], 0, 0, 0);
            }
        }
        __syncthreads();
        cur ^= 1;
    }

    const int nb2 = (n0 >> 6) * 2 + wn;                  // 0..31
#pragma unroll
    for (int mi = 0; mi < 4; ++mi) {
        const int row0 = m0 + wm * 64 + mi * 16 + lhi * 4;
        float vmn[4], vmx[4];
#pragma unroll
        for (int nj = 0; nj < 2; ++nj) {
            const int col = n0 + wn * 32 + nj * 16 + l15;
            const float bv = b1[col];
#pragma unroll
            for (int j = 0; j < 4; ++j) {
                f16 hv = (f16)(acc[mi][nj][j] + bv);
                h[(size_t)(row0 + j) * NEURONS + col] = hv;
                float vr = (float)hv;                    // min/max of ROUNDED value
                if (nj == 0) { vmn[j] = vr; vmx[j] = vr; }
                else { vmn[j] = fminf(vmn[j], vr); vmx[j] = fmaxf(vmx[j], vr); }
            }
        }
#pragma unroll
        for (int j = 0; j < 4; ++j) {
#pragma unroll
            for (int d = 1; d < 16; d <<= 1) {
                vmn[j] = fminf(vmn[j], __shfl_xor(vmn[j], d));
                vmx[j] = fmaxf(vmx[j], __shfl_xor(vmx[j], d));
            }
        }
        if (l15 == 0) {
#pragma unroll
            for (int j = 0; j < 4; ++j) {
                pmin[(size_t)nb2 * M_ROWS + row0 + j] = vmn[j];
                pmax[(size_t)nb2 * M_ROWS + row0 + j] = vmx[j];
            }
        }
    }
}

// ===========================================================================
// k_sp_gemm2: out = relu(spline(norm(h)) @ W2 + b2)
// BM=16, BN=256, 512 blocks. Per K-step the 16x64 A-tile is spline-computed
// JIT into padded LDS (shared by all 4 waves); B staged via global_load_lds
// from pre-swizzled W2t with XOR on ds_read. Dbuf, 1 barrier/step.
// ===========================================================================
__global__ __launch_bounds__(256) void k_sp_gemm2(
    const f16* __restrict__ h, const float* __restrict__ pmin,
    const float* __restrict__ pmax, const float* __restrict__ cp,
    const f16* __restrict__ W2t, const float* __restrict__ b2,
    float* __restrict__ out)
{
    __shared__ __align__(16) f16 Bb[2][256 * 64];        // 64 KB
    __shared__ __align__(16) f16 Aa[2][16 * 72];         // 4.5 KB (padded)
    __shared__ float red[2][16][17];                     // partial transpose
    __shared__ float mnS[16], invS[16];

    const int t    = threadIdx.x;
    const int lane = t & 63, l15 = lane & 15, lhi = lane >> 4;
    const int wid  = t >> 6;

    const int flat = blockIdx.x;                         // 512 blocks
    const int swz  = (flat & 7) * 64 + (flat >> 3);
    const int m0   = (swz >> 1) * 16;                    // 256 m-tiles
    const int n0   = (swz & 1) * 256;                    // 2 n-tiles

    // ---- prologue: reduce 32 min/max partials -> mn, inv per row ----------
    {
        const int r_ = t & 15, p = t >> 4;               // 16 rows x 16 pairs
        const int row = m0 + r_;
        red[0][r_][p] = fminf(pmin[(size_t)p * M_ROWS + row],
                              pmin[(size_t)(p + 16) * M_ROWS + row]);
        red[1][r_][p] = fmaxf(pmax[(size_t)p * M_ROWS + row],
                              pmax[(size_t)(p + 16) * M_ROWS + row]);
    }
    __syncthreads();
    if (t < 16) {
        float a = red[0][t][0], b = red[1][t][0];
#pragma unroll
        for (int p = 1; p < 16; ++p) {
            a = fminf(a, red[0][t][p]);
            b = fmaxf(b, red[1][t][p]);
        }
        mnS[t] = a;
        invS[t] = 1.0f / (b - a + 1e-8f);
    }

    auto stageB = [&](int bf, int tt) {
        char* base = (char*)&Bb[bf][0] + wid * 8192;     // 64 rows/wave
#pragma unroll
        for (int j = 0; j < 8; ++j) {
            const int r = wid * 64 + j * 8 + (lane >> 3);
            const char* src = (const char*)W2t + (size_t)(n0 + r) * 2048
                              + tt * 128 + (lane & 7) * 16;
            __builtin_amdgcn_global_load_lds(
                (const __attribute__((address_space(1))) void*)src,
                (__attribute__((address_space(3))) void*)(base + j * 1024), 16, 0, 0);
        }
    };
    auto splineA = [&](int bf, int tt) {
        const int r_ = t >> 4;                           // 0..15
        const int k4 = (t & 15) * 4;                     // 0..60
        const int kg = tt * 64 + k4;
        f16x4 hv = *(const f16x4*)&h[(size_t)(m0 + r_) * NEURONS + kg];
        const float mn = mnS[r_], inv = invS[r_];
        f16x4 o;
#pragma unroll
        for (int e = 0; e < 4; ++e) {
            const float u   = ((float)hv[e] - mn) * inv;
            const float t15 = u * 15.0f;
            int ii = (int)t15;
            ii = ii < 0 ? 0 : (ii > 14 ? 14 : ii);
            const float tl  = t15 - (float)ii;
            const float t2  = tl * tl, t3 = t2 * tl;
            const float omt = 1.0f - tl;
            const float b0  = omt * omt * omt * (1.0f / 6.0f);
            const float b3v = t3 * (1.0f / 6.0f);
            const float b1v = (4.0f / 6.0f) - t2 + 0.5f * t3;
            const float b2v = (1.0f / 6.0f) + 0.5f * (tl + t2 - t3);
            const float4 c  = *(const float4*)&cp[((size_t)(kg + e) * 15 + ii) * 4];
            o[e] = (f16)(c.x * b0 + c.y * b1v + c.z * b2v + c.w * b3v);
        }
        *(f16x4*)&Aa[bf][r_ * 72 + k4] = o;
    };

    f32x4 acc[4];
#pragma unroll
    for (int j = 0; j < 4; ++j) acc[j] = (f32x4)0.f;

    stageB(0, 0);
    __syncthreads();           // mnS/invS ready; B(0) staged (vmcnt drained)
    splineA(0, 0);
    __syncthreads();

    int cur = 0;
    for (int tt = 0; tt < 16; ++tt) {                    // K = 1024
        if (tt < 15) {
            stageB(cur ^ 1, tt + 1);
            splineA(cur ^ 1, tt + 1);
        }
        const char* B_ = (const char*)&Bb[cur][0];
#pragma unroll
        for (int ks = 0; ks < 2; ++ks) {
            f16x8 afr = *(const f16x8*)&Aa[cur][l15 * 72 + ks * 32 + lhi * 8];
#pragma unroll
            for (int nj = 0; nj < 4; ++nj) {
                const int cl = wid * 64 + nj * 16 + l15;
                const int kb = (ks * 64 + lhi * 16) ^ ((cl & 7) << 4);
                f16x8 bfr = *(const f16x8*)(B_ + (size_t)cl * 128 + kb);
                acc[nj] = __builtin_amdgcn_mfma_f32_16x16x32_f16(afr, bfr, acc[nj], 0, 0, 0);
            }
        }
        __syncthreads();
        cur ^= 1;
    }

    // epilogue: col = l15-map, row = lhi*4 + j
#pragma unroll
    for (int nj = 0; nj < 4; ++nj) {
        const int col = n0 + wid * 64 + nj * 16 + l15;
        const float bv = b2[col];
        const int row0 = m0 + lhi * 4;
#pragma unroll
        for (int j = 0; j < 4; ++j)
            out[(size_t)(row0 + j) * OUT_DIM + col] = fmaxf(acc[nj][j] + bv, 0.0f);
    }
}

// ===========================================================================
extern "C" void kernel_launch(void* const* d_in, const int* in_sizes, int n_in,
                              void* d_out, int out_size, void* d_ws, size_t ws_size,
                              hipStream_t stream)
{
    const float* x     = (const float*)d_in[0];
    const float* W1    = (const float*)d_in[1];
    const float* b1    = (const float*)d_in[2];
    const float* coeff = (const float*)d_in[3];
    const float* spb   = (const float*)d_in[4];
    const float* W2    = (const float*)d_in[5];
    const float* b2    = (const float*)d_in[6];
    float* out = (float*)d_out;

    char* ws = (char*)d_ws;
    f16*   h    = (f16*)ws;                                  //  8 MB [4096][1024]
    f16*   xh   = (f16*)(ws + ( 8u << 20));                  //  4 MB [4096][512]
    f16*   W1t  = (f16*)(ws + (12u << 20));                  //  1 MB [1024][512]
    f16*   W2t  = (f16*)(ws + (13u << 20));                  //  1 MB [512][1024] swizzled
    float* pmin = (float*)(ws + (14u << 20));                // 512 KB [32][4096]
    float* pmax = (float*)(ws + (14u << 20) + (512u << 10)); // 512 KB
    float* cp   = (float*)(ws + (15u << 20));                // 960 KB [1024][15][4]

    prep<<<dim3(2108), 256, 0, stream>>>(x, xh, W1, W1t, W2, W2t, coeff, spb, cp);

    k_gemm1<<<dim3(16, 32), 256, 0, stream>>>(xh, W1t, b1, h, pmin, pmax);

    k_sp_gemm2<<<dim3(512), 256, 0, stream>>>(h, pmin, pmax, cp, W2t, b2, out);
}